// Round 3
// baseline (74410.651 us; speedup 1.0000x reference)
//
#include <hip/hip_runtime.h>

#define T_STEPS 8192
#define HDIM 1024
#define NL0 64            // layer-0 workgroups
#define NL1 128           // layer-1 workgroups
#define NWG (NL0 + NL1)   // 192 compute WGs (+1 monitor)
#define RING 16           // h-ring depth (slots)
#define WM_SLACK 12       // store step p requires watermark >= p-WM_SLACK (exact bound p-15)
#define PVALVE 3000000L   // global poll valve (~1 s)
#define SVALVE 50000000L  // LDS spin valve
typedef unsigned long long u64;

// ---------- helpers ----------
__device__ __forceinline__ float wred(float v) {
#pragma unroll
    for (int s = 32; s >= 1; s >>= 1) v += __shfl_xor(v, s, 64);
    return v;
}
__device__ __forceinline__ int wred_min(int v) {
#pragma unroll
    for (int s = 32; s >= 1; s >>= 1) v = min(v, __shfl_xor(v, s, 64));
    return v;
}
__device__ __forceinline__ float sigm(float x) { return 1.0f / (1.0f + expf(-x)); }

__device__ __forceinline__ void st_coh_i32(int* p, int v) {
    asm volatile("global_store_dword %0, %1, off sc0 sc1" :: "v"(p), "v"(v) : "memory");
}
__device__ __forceinline__ void st_pair(u64* p, u64 v) {
    asm volatile("global_store_dwordx2 %0, %1, off sc0 sc1" :: "v"(p), "v"(v) : "memory");
}
__device__ __forceinline__ int ld_coh_i32(const int* p) {
    int v;
    asm volatile("global_load_dword %0, %1, off sc0 sc1\n\ts_waitcnt vmcnt(0)"
                 : "=&v"(v) : "v"(p) : "memory");
    return v;
}
// 2 packed pairs (stride 512B) + watermark + abort, one batch.
__device__ __forceinline__ void ld2p_wf(const u64* p, const int* wmp,
                                        u64& a, u64& b, int& wm, int& ab) {
    asm volatile(
        "global_load_dwordx2 %0, %4, off sc0 sc1\n\t"
        "global_load_dwordx2 %1, %4, off offset:512 sc0 sc1\n\t"
        "global_load_dword %2, %5, off sc0 sc1\n\t"
        "global_load_dword %3, %5, off offset:4 sc0 sc1\n\t"
        "s_waitcnt vmcnt(0)"
        : "=&v"(a), "=&v"(b), "=&v"(wm), "=&v"(ab)
        : "v"(p), "v"(wmp) : "memory");
}
// 4 packed pairs (stride 512B) + watermark + abort.
__device__ __forceinline__ void ld4p_wf(const u64* p, const int* wmp,
                                        u64& a, u64& b, u64& c, u64& d, int& wm, int& ab) {
    asm volatile(
        "global_load_dwordx2 %0, %6, off sc0 sc1\n\t"
        "global_load_dwordx2 %1, %6, off offset:512 sc0 sc1\n\t"
        "global_load_dwordx2 %2, %6, off offset:1024 sc0 sc1\n\t"
        "global_load_dwordx2 %3, %6, off offset:1536 sc0 sc1\n\t"
        "global_load_dword %4, %7, off sc0 sc1\n\t"
        "global_load_dword %5, %7, off offset:4 sc0 sc1\n\t"
        "s_waitcnt vmcnt(0)"
        : "=&v"(a), "=&v"(b), "=&v"(c), "=&v"(d), "=&v"(wm), "=&v"(ab)
        : "v"(p), "v"(wmp) : "memory");
}
__device__ __forceinline__ u64 pack(float h, int tag) {
    return ((u64)(unsigned)tag << 32) | (u64)__float_as_uint(h);
}
__device__ __forceinline__ float pval(u64 q) { return __uint_as_float((unsigned)q); }
__device__ __forceinline__ unsigned ptag(u64 q) { return (unsigned)(q >> 32); }

// ---------- prologue ----------
__global__ void lstm_prologue(const float* __restrict__ Wih0, const float* __restrict__ Win,
                              const float* __restrict__ bin, const float* __restrict__ bih0,
                              const float* __restrict__ bhh0, const float* __restrict__ bih1,
                              const float* __restrict__ bhh1,
                              float* __restrict__ U, float* __restrict__ V, float* __restrict__ B1) {
    const int wv = threadIdx.x >> 6, lane = threadIdx.x & 63;
    const int r = blockIdx.x * 4 + wv;
    const float* wp = Wih0 + (size_t)r * HDIM;
    float au = 0.f, av = 0.f;
#pragma unroll
    for (int j = 0; j < 16; ++j) {
        float wj = wp[lane + 64 * j];
        au += wj * Win[lane + 64 * j];
        av += wj * bin[lane + 64 * j];
    }
    au = wred(au);
    av = wred(av);
    if (lane == 0) {
        U[r] = au;
        V[r] = av + bih0[r] + bhh0[r];
        B1[r] = bih1[r] + bhh1[r];
    }
}

// ---------- persistent async-dataflow LSTM ----------
__global__ __launch_bounds__(512, 1) void lstm_persistent(
    const float* __restrict__ inputs, const float* __restrict__ Whh0,
    const float* __restrict__ Wih1, const float* __restrict__ Whh1,
    const float* __restrict__ Wout, int* flags, u64* h0q, u64* h1q,
    const float* __restrict__ U, const float* __restrict__ V, const float* __restrict__ B1,
    float* part) {
    __shared__ float kbuf[2][2048];
    __shared__ int rdy[2];
    const int tid = threadIdx.x;
    const int wv = tid >> 6;
    const int lane = tid & 63;
    const int wg = blockIdx.x;
    int* wmp = flags + 256;       // watermark; abort at flags[257]
    int* abp = flags + 257;

    if (wg == NWG) {
        // ---- monitor: publish watermark = min over 192 WG progress words ----
        if (tid >= 64) return;
        const int* pr = flags + lane;
        long it = 0;
        for (;;) {
            int a, b, c, ab;
            asm volatile(
                "global_load_dword %0, %4, off sc0 sc1\n\t"
                "global_load_dword %1, %4, off offset:256 sc0 sc1\n\t"
                "global_load_dword %2, %4, off offset:512 sc0 sc1\n\t"
                "global_load_dword %3, %5, off offset:4 sc0 sc1\n\t"
                "s_waitcnt vmcnt(0)"
                : "=&v"(a), "=&v"(b), "=&v"(c), "=&v"(ab)
                : "v"(pr), "v"(wmp) : "memory");
            int m = wred_min(min(a, min(b, c)));
            if (lane == 0) st_coh_i32(wmp, m);
            if (m >= T_STEPS - 1 || ab) break;
            if (++it > PVALVE) { if (lane == 0) st_coh_i32(abp, 1); break; }
        }
        return;
    }

    if (tid == 0) { rdy[0] = 0; rdy[1] = 0; }
    __syncthreads();   // once, before the loop — init of LDS counters only

    int wm_cache = 0;
    bool aborted = false;

    if (wg < NL0) {
        // ---- layer 0: WG owns 16 h-elems; wave wv owns elems base_e,base_e+1 (8 gate rows).
        const int base_e = wg * 16 + wv * 2;
        float w[8][16];
        float uu[2][4], vv[2][4];
#pragma unroll
        for (int j = 0; j < 2; ++j)
#pragma unroll
            for (int g = 0; g < 4; ++g) {
                const int row = g * HDIM + base_e + j;
                const float* pw = Whh0 + (size_t)row * HDIM;
#pragma unroll
                for (int k = 0; k < 16; ++k) w[j * 4 + g][k] = pw[lane + 64 * k];
                uu[j][g] = U[row];
                vv[j][g] = V[row];
            }
        const int se = wv * 128 + lane;   // this lane stages h0 elems se, se+64
        float c0 = 0.f, c1 = 0.f;
        for (int p = 0; p < T_STEPS && !aborted; ++p) {
            const int par = p & 1;
            const float st = inputs[p];
            // stage h0[p-1] (tag == p) into LDS
            {
                const u64* src = h0q + ((p - 1) & (RING - 1)) * HDIM + se;
                u64 a, b; int ab;
                long it = 0;
                for (;;) {
                    ld2p_wf(src, wmp, a, b, wm_cache, ab);
                    unsigned d = (ptag(a) ^ (unsigned)p) | (ptag(b) ^ (unsigned)p);
                    if (__all(d == 0)) break;
                    if (ab) { aborted = true; break; }
                    if (++it > PVALVE) { st_coh_i32(abp, 1); aborted = true; break; }
                }
                if (aborted) break;
                kbuf[par][se] = pval(a);
                kbuf[par][se + 64] = pval(b);
            }
            const int tgt = 8 * ((p >> 1) + 1);
            if (lane == 0) {
                int old = __hip_atomic_fetch_add(&rdy[par], 1, __ATOMIC_RELEASE,
                                                 __HIP_MEMORY_SCOPE_WORKGROUP);
                if (old == tgt - 1) st_coh_i32(flags + wg, p);   // WG progress = staged step
            }
            long its = 0;
            while (__hip_atomic_load(&rdy[par], __ATOMIC_ACQUIRE,
                                     __HIP_MEMORY_SCOPE_WORKGROUP) < tgt) {
                if (++its > SVALVE) { st_coh_i32(abp, 1); aborted = true; break; }
            }
            if (aborted) break;
            // consume
            float hv[16];
#pragma unroll
            for (int j = 0; j < 16; ++j) hv[j] = kbuf[par][lane + 64 * j];
            float acc[8];
#pragma unroll
            for (int r = 0; r < 8; ++r) {
                float a = 0.f;
#pragma unroll
                for (int k = 0; k < 16; ++k) a += w[r][k] * hv[k];
                acc[r] = a;
            }
#pragma unroll
            for (int r = 0; r < 8; ++r) acc[r] = wred(acc[r]);
            float gi = acc[0] + st * uu[0][0] + vv[0][0];
            float gf = acc[1] + st * uu[0][1] + vv[0][1];
            float gg = acc[2] + st * uu[0][2] + vv[0][2];
            float go = acc[3] + st * uu[0][3] + vv[0][3];
            float cn0 = sigm(gf) * c0 + sigm(gi) * tanhf(gg);
            float hn0 = sigm(go) * tanhf(cn0);
            c0 = cn0;
            gi = acc[4] + st * uu[1][0] + vv[1][0];
            gf = acc[5] + st * uu[1][1] + vv[1][1];
            gg = acc[6] + st * uu[1][2] + vv[1][2];
            go = acc[7] + st * uu[1][3] + vv[1][3];
            float cn1 = sigm(gf) * c1 + sigm(gi) * tanhf(gg);
            float hn1 = sigm(go) * tanhf(cn1);
            c1 = cn1;
            // backpressure, then publish h0[p]
            long itw = 0;
            while (wm_cache < p - WM_SLACK) {
                wm_cache = ld_coh_i32(wmp);
                if (ld_coh_i32(abp)) { aborted = true; break; }
                if (++itw > PVALVE) { st_coh_i32(abp, 1); aborted = true; break; }
            }
            if (aborted) break;
            if (lane == 0) {
                u64* dst = h0q + (p & (RING - 1)) * HDIM + base_e;
                st_pair(dst, pack(hn0, p + 1));
                st_pair(dst + 1, pack(hn1, p + 1));
            }
        }
    } else {
        // ---- layer 1: WG owns 8 h-elems; wave wv owns elem e (4 rows, K=2048). ----
        const int wgb = wg - NL0;
        const int e = wgb * 8 + wv;
        const int hl = lane & 31;
        const float* wsrc = (lane < 32) ? Wih1 : Whh1;
        float w[4][32];
        float bb[4];
#pragma unroll
        for (int g = 0; g < 4; ++g) {
            const int row = g * HDIM + e;
            const float* pw = wsrc + (size_t)row * HDIM;
#pragma unroll
            for (int k = 0; k < 32; ++k) w[g][k] = pw[hl + 32 * k];
            bb[g] = B1[row];
        }
        const float woute = Wout[e];
        // staging: wave wv stages combined K-indices c = wv*256 + lane + 64k, k=0..3
        // wv<4 -> h0[t] (tag t+1); wv>=4 -> h1[t-1] (tag t)
        const int cbase = wv * 256 + lane;
        float c1s = 0.f;
        for (int t = 0; t < T_STEPS && !aborted; ++t) {
            const int par = t & 1;
            {
                const u64* src = (wv < 4)
                    ? (h0q + (t & (RING - 1)) * HDIM + cbase)
                    : (h1q + ((t - 1) & (RING - 1)) * HDIM + (cbase - 1024));
                const unsigned exp = (wv < 4) ? (unsigned)(t + 1) : (unsigned)t;
                u64 a, b, c, d; int ab;
                long it = 0;
                for (;;) {
                    ld4p_wf(src, wmp, a, b, c, d, wm_cache, ab);
                    unsigned dd = (ptag(a) ^ exp) | (ptag(b) ^ exp) |
                                  (ptag(c) ^ exp) | (ptag(d) ^ exp);
                    if (__all(dd == 0)) break;
                    if (ab) { aborted = true; break; }
                    if (++it > PVALVE) { st_coh_i32(abp, 1); aborted = true; break; }
                }
                if (aborted) break;
                kbuf[par][cbase] = pval(a);
                kbuf[par][cbase + 64] = pval(b);
                kbuf[par][cbase + 128] = pval(c);
                kbuf[par][cbase + 192] = pval(d);
            }
            const int tgt = 8 * ((t >> 1) + 1);
            if (lane == 0) {
                int old = __hip_atomic_fetch_add(&rdy[par], 1, __ATOMIC_RELEASE,
                                                 __HIP_MEMORY_SCOPE_WORKGROUP);
                if (old == tgt - 1) st_coh_i32(flags + wg, t);
            }
            long its = 0;
            while (__hip_atomic_load(&rdy[par], __ATOMIC_ACQUIRE,
                                     __HIP_MEMORY_SCOPE_WORKGROUP) < tgt) {
                if (++its > SVALVE) { st_coh_i32(abp, 1); aborted = true; break; }
            }
            if (aborted) break;
            const int koff = (lane < 32) ? 0 : 1024;
            float hv[32];
#pragma unroll
            for (int j = 0; j < 32; ++j) hv[j] = kbuf[par][koff + hl + 32 * j];
            float acc[4];
#pragma unroll
            for (int g = 0; g < 4; ++g) {
                float a = 0.f;
#pragma unroll
                for (int k = 0; k < 32; ++k) a += w[g][k] * hv[k];
                acc[g] = a;
            }
#pragma unroll
            for (int g = 0; g < 4; ++g) acc[g] = wred(acc[g]);
            const float gi = acc[0] + bb[0];
            const float gf = acc[1] + bb[1];
            const float gg = acc[2] + bb[2];
            const float go = acc[3] + bb[3];
            const float cn = sigm(gf) * c1s + sigm(gi) * tanhf(gg);
            const float hn = sigm(go) * tanhf(cn);
            c1s = cn;
            long itw = 0;
            while (wm_cache < t - WM_SLACK) {
                wm_cache = ld_coh_i32(wmp);
                if (ld_coh_i32(abp)) { aborted = true; break; }
                if (++itw > PVALVE) { st_coh_i32(abp, 1); aborted = true; break; }
            }
            if (aborted) break;
            if (lane == 0) {
                st_pair(h1q + (t & (RING - 1)) * HDIM + e, pack(hn, t + 1));
                atomicAdd(part + (size_t)t * 64 + (e >> 4), woute * hn);
            }
        }
    }
}

// ---------- output projection ----------
__global__ void lstm_finalize(const float* __restrict__ part, const float* __restrict__ bout,
                              float* __restrict__ out) {
    const int t = blockIdx.x * 256 + threadIdx.x;
    if (t < T_STEPS) {
        const float4* p4 = (const float4*)(part + (size_t)t * 64);
        float s = bout[0];
#pragma unroll
        for (int i = 0; i < 16; ++i) {
            float4 v = p4[i];
            s += v.x + v.y + v.z + v.w;
        }
        out[t] = s;
    }
}

extern "C" void kernel_launch(void* const* d_in, const int* in_sizes, int n_in,
                              void* d_out, int out_size, void* d_ws, size_t ws_size,
                              hipStream_t stream) {
    const float* inputs = (const float*)d_in[0];
    const float* Win  = (const float*)d_in[1];
    const float* bin  = (const float*)d_in[2];
    const float* Wih0 = (const float*)d_in[3];
    const float* Whh0 = (const float*)d_in[4];
    const float* bih0 = (const float*)d_in[5];
    const float* bhh0 = (const float*)d_in[6];
    const float* Wih1 = (const float*)d_in[7];
    const float* Whh1 = (const float*)d_in[8];
    const float* bih1 = (const float*)d_in[9];
    const float* bhh1 = (const float*)d_in[10];
    const float* Wout = (const float*)d_in[11];
    const float* bout = (const float*)d_in[12];

    char* ws = (char*)d_ws;
    int*  flags = (int*)ws;                       // [0..191] progress, [256] wm, [257] abort
    u64*  h0q   = (u64*)(ws + 4096);              // RING*1024*8 = 128 KB
    u64*  h1q   = (u64*)(ws + 4096 + 131072);     // 128 KB (ends 266240)
    float* part = (float*)(ws + 266240);          // T*64*4 = 2 MB (ends 2363392)
    float* U    = (float*)(ws + 2363392);         // 16 KB
    float* V    = (float*)(ws + 2379776);         // 16 KB
    float* B1   = (float*)(ws + 2396160);         // 16 KB (ends 2412544)

    if (ws_size < (size_t)2412544) return;

    hipMemsetAsync(ws, 0, 266240, stream);                  // flags + wm + abort + rings
    hipMemsetAsync(ws + 266240, 0, 2097152, stream);        // part

    lstm_prologue<<<1024, 256, 0, stream>>>(Wih0, Win, bin, bih0, bhh0, bih1, bhh1, U, V, B1);
    lstm_persistent<<<NWG + 1, 512, 0, stream>>>(inputs, Whh0, Wih1, Whh1, Wout,
                                                 flags, h0q, h1q, U, V, B1, part);
    lstm_finalize<<<(T_STEPS + 255) / 256, 256, 0, stream>>>(part, bout, (float*)d_out);
}

// Round 4
// 48344.958 us; speedup vs baseline: 1.5392x; 1.5392x over previous
//
#include <hip/hip_runtime.h>

#define T_STEPS 8192
#define HDIM 1024
#define NL0 64            // layer-0 workgroups
#define NL1 128           // layer-1 workgroups
#define NWG (NL0 + NL1)   // compute WGs (+1 monitor)
#define RING 64           // h-ring depth (slots): ~40-step producer lead allowed
#define RMASK 63
#define PVALVE 300000L    // valve iterations (~0.1 s)
typedef unsigned long long u64;

// ---------- helpers ----------
__device__ __forceinline__ float wred(float v) {
#pragma unroll
    for (int s = 32; s >= 1; s >>= 1) v += __shfl_xor(v, s, 64);
    return v;
}
__device__ __forceinline__ int wred_min(int v) {
#pragma unroll
    for (int s = 32; s >= 1; s >>= 1) v = min(v, __shfl_xor(v, s, 64));
    return v;
}
__device__ __forceinline__ float sigm(float x) { return 1.0f / (1.0f + expf(-x)); }

__device__ __forceinline__ void st_coh_i32(int* p, int v) {
    asm volatile("global_store_dword %0, %1, off sc0 sc1" :: "v"(p), "v"(v) : "memory");
}
__device__ __forceinline__ int ld_coh_i32(const int* p) {
    int v;
    asm volatile("global_load_dword %0, %1, off sc0 sc1\n\ts_waitcnt vmcnt(0)"
                 : "=&v"(v) : "v"(p) : "memory");
    return v;
}
__device__ __forceinline__ void st_pair(u64* p, u64 v) {
    asm volatile("global_store_dwordx2 %0, %1, off sc0 sc1" :: "v"(p), "v"(v) : "memory");
}
// pure data polls: NO shared hot lines in the batch
__device__ __forceinline__ void ld2p(const u64* p, u64& a, u64& b) {
    asm volatile(
        "global_load_dwordx2 %0, %2, off sc0 sc1\n\t"
        "global_load_dwordx2 %1, %2, off offset:512 sc0 sc1\n\t"
        "s_waitcnt vmcnt(0)"
        : "=&v"(a), "=&v"(b) : "v"(p) : "memory");
}
__device__ __forceinline__ void ld4p(const u64* p, u64& a, u64& b, u64& c, u64& d) {
    asm volatile(
        "global_load_dwordx2 %0, %4, off sc0 sc1\n\t"
        "global_load_dwordx2 %1, %4, off offset:512 sc0 sc1\n\t"
        "global_load_dwordx2 %2, %4, off offset:1024 sc0 sc1\n\t"
        "global_load_dwordx2 %3, %4, off offset:1536 sc0 sc1\n\t"
        "s_waitcnt vmcnt(0)"
        : "=&v"(a), "=&v"(b), "=&v"(c), "=&v"(d) : "v"(p) : "memory");
}
__device__ __forceinline__ u64 pack(float h, int tag) {
    return ((u64)(unsigned)tag << 32) | (u64)__float_as_uint(h);
}
__device__ __forceinline__ float pval(u64 q) { return __uint_as_float((unsigned)q); }
__device__ __forceinline__ unsigned ptag(u64 q) { return (unsigned)(q >> 32); }

// ---------- prologue: U = Wih0*Win, V = Wih0*bin + bih0 + bhh0, B1 = bih1 + bhh1 ----------
__global__ void lstm_prologue(const float* __restrict__ Wih0, const float* __restrict__ Win,
                              const float* __restrict__ bin, const float* __restrict__ bih0,
                              const float* __restrict__ bhh0, const float* __restrict__ bih1,
                              const float* __restrict__ bhh1,
                              float* __restrict__ U, float* __restrict__ V, float* __restrict__ B1) {
    const int wv = threadIdx.x >> 6, lane = threadIdx.x & 63;
    const int r = blockIdx.x * 4 + wv;
    const float* wp = Wih0 + (size_t)r * HDIM;
    float au = 0.f, av = 0.f;
#pragma unroll
    for (int j = 0; j < 16; ++j) {
        float wj = wp[lane + 64 * j];
        au += wj * Win[lane + 64 * j];
        av += wj * bin[lane + 64 * j];
    }
    au = wred(au);
    av = wred(av);
    if (lane == 0) {
        U[r] = au;
        V[r] = av + bih0[r] + bhh0[r];
        B1[r] = bih1[r] + bhh1[r];
    }
}

// ---------- persistent async-dataflow LSTM (tag-in-data, no barriers, no hot lines) ----------
// flags[wg*4]: per-WG progress (16B stride). flags[768]: floor. flags[784]: abort.
__global__ __launch_bounds__(512, 1) void lstm_persistent(
    const float* __restrict__ inputs, const float* __restrict__ Whh0,
    const float* __restrict__ Wih1, const float* __restrict__ Whh1,
    const float* __restrict__ Wout, int* flags, u64* h0q, u64* h1q,
    const float* __restrict__ U, const float* __restrict__ V, const float* __restrict__ B1,
    float* part) {
    __shared__ float kbuf[2][2048];
    __shared__ float ibuf[T_STEPS];
    __shared__ float osum[2][8];
    __shared__ int lds_ab;
    const int tid = threadIdx.x;
    const int wv = tid >> 6;
    const int lane = tid & 63;
    const int wg = blockIdx.x;
    int* flp = flags + 768;
    int* abp = flags + 784;

    if (wg == NWG) {
        // ---- monitor: floor = min over 192 WG progress words; publish once per sweep ----
        if (tid >= 64) return;
        const int* pr = flags + lane * 4;
        long it = 0;
        for (;;) {
            int a, b, c;
            asm volatile(
                "global_load_dword %0, %3, off sc0 sc1\n\t"
                "global_load_dword %1, %3, off offset:1024 sc0 sc1\n\t"
                "global_load_dword %2, %3, off offset:2048 sc0 sc1\n\t"
                "s_waitcnt vmcnt(0)"
                : "=&v"(a), "=&v"(b), "=&v"(c) : "v"(pr) : "memory");
            int m = wred_min(min(a, min(b, c)));
            if (lane == 0) st_coh_i32(flp, m);
            if (m >= T_STEPS) break;
            if ((++it & 63) == 0) {
                if (ld_coh_i32(abp)) break;
                if (it > PVALVE) { if (lane == 0) st_coh_i32(abp, 1); break; }
            }
        }
        return;
    }

    if (tid == 0) lds_ab = 0;

    if (wg < NL0) {
        // ---- layer 0: WG owns 16 h-elems; wave wv owns elems base_e, base_e+1 (8 gate rows).
        const int base_e = wg * 16 + wv * 2;
        float w[8][16];
        float uu[2][4], vv[2][4];
#pragma unroll
        for (int j = 0; j < 2; ++j)
#pragma unroll
            for (int g = 0; g < 4; ++g) {
                const int row = g * HDIM + base_e + j;
                const float* pw = Whh0 + (size_t)row * HDIM;
#pragma unroll
                for (int k = 0; k < 16; ++k) w[j * 4 + g][k] = pw[lane + 64 * k];
                uu[j][g] = U[row];
                vv[j][g] = V[row];
            }
#pragma unroll
        for (int k = 0; k < 16; ++k) ibuf[tid + 512 * k] = inputs[tid + 512 * k];
        __syncthreads();

        const int se = wv * 128 + lane;   // stages h0 elems se, se+64
        float c0 = 0.f, c1 = 0.f;
        for (int p = 0; p < T_STEPS; ++p) {
            const int par = p & 1;
            // poll-stage h0[p-1] (tag p) from slot (p-1)&63 — pure data poll
            const u64* src = h0q + (size_t)((p - 1) & RMASK) * HDIM + se;
            u64 a, b;
            long it = 0;
            const unsigned xt = (unsigned)p;
            for (;;) {
                ld2p(src, a, b);
                if (__all(((ptag(a) ^ xt) | (ptag(b) ^ xt)) == 0)) break;
                if ((++it & 255) == 0) {
                    if (ld_coh_i32(abp) || it > PVALVE) {
                        st_coh_i32(abp, 1); lds_ab = 1; break;
                    }
                }
            }
            kbuf[par][se] = pval(a);
            kbuf[par][se + 64] = pval(b);
            __syncthreads();
            if (lds_ab) break;
            if (tid == 0) st_coh_i32(flags + wg * 4, p);   // consumed slot p-1
            // compute
            float hv[16];
#pragma unroll
            for (int j = 0; j < 16; ++j) hv[j] = kbuf[par][lane + 64 * j];
            float acc[8];
#pragma unroll
            for (int r = 0; r < 8; ++r) {
                float s = 0.f;
#pragma unroll
                for (int k = 0; k < 16; ++k) s += w[r][k] * hv[k];
                acc[r] = s;
            }
#pragma unroll
            for (int r = 0; r < 8; ++r) acc[r] = wred(acc[r]);
            const float st = ibuf[p];
            float gi = acc[0] + st * uu[0][0] + vv[0][0];
            float gf = acc[1] + st * uu[0][1] + vv[0][1];
            float gg = acc[2] + st * uu[0][2] + vv[0][2];
            float go = acc[3] + st * uu[0][3] + vv[0][3];
            float cn0 = sigm(gf) * c0 + sigm(gi) * tanhf(gg);
            float hn0 = sigm(go) * tanhf(cn0);
            c0 = cn0;
            gi = acc[4] + st * uu[1][0] + vv[1][0];
            gf = acc[5] + st * uu[1][1] + vv[1][1];
            gg = acc[6] + st * uu[1][2] + vv[1][2];
            go = acc[7] + st * uu[1][3] + vv[1][3];
            float cn1 = sigm(gf) * c1 + sigm(gi) * tanhf(gg);
            float hn1 = sigm(go) * tanhf(cn1);
            c1 = cn1;
            // lazy ring backpressure: every 8 steps, require floor >= p-40 (exact bound p-63)
            if (p >= 48 && (p & 7) == 0) {
                long itf = 0;
                for (;;) {
                    int fl = ld_coh_i32(flp);
                    if (fl >= p - 40) break;
                    if (ld_coh_i32(abp)) break;
                    if (++itf > PVALVE) { st_coh_i32(abp, 1); break; }
                }
            }
            if (lane == 0) {
                u64* dst = h0q + (size_t)(p & RMASK) * HDIM + base_e;
                st_pair(dst, pack(hn0, p + 1));
                st_pair(dst + 1, pack(hn1, p + 1));
            }
        }
        __syncthreads();
        if (tid == 0) st_coh_i32(flags + wg * 4, T_STEPS);
    } else {
        // ---- layer 1: WG owns 8 h-elems; wave wv owns elem e (4 rows, K=2048). ----
        const int wgb = wg - NL0;
        const int e = wgb * 8 + wv;
        const int hl = lane & 31;
        const float* wsrc = (lane < 32) ? Wih1 : Whh1;
        float w[4][32];
        float bb[4];
#pragma unroll
        for (int g = 0; g < 4; ++g) {
            const int row = g * HDIM + e;
            const float* pw = wsrc + (size_t)row * HDIM;
#pragma unroll
            for (int k = 0; k < 32; ++k) w[g][k] = pw[hl + 32 * k];
            bb[g] = B1[row];
        }
        const float woute = Wout[e];
        // staging: wave wv stages combined K-indices cbase + {0,64,128,192}
        // wv<4 -> h0[t] (tag t+1); wv>=4 -> h1[t-1] (tag t)
        const int cbase = wv * 256 + lane;
        __syncthreads();
        float c1s = 0.f;
        for (int t = 0; t < T_STEPS; ++t) {
            const int par = t & 1;
            const u64* src = (wv < 4)
                ? (h0q + (size_t)(t & RMASK) * HDIM + cbase)
                : (h1q + (size_t)((t - 1) & RMASK) * HDIM + (cbase - 1024));
            const unsigned xt = (wv < 4) ? (unsigned)(t + 1) : (unsigned)t;
            u64 a, b, c, d;
            long it = 0;
            for (;;) {
                ld4p(src, a, b, c, d);
                unsigned dd = (ptag(a) ^ xt) | (ptag(b) ^ xt) |
                              (ptag(c) ^ xt) | (ptag(d) ^ xt);
                if (__all(dd == 0)) break;
                if ((++it & 255) == 0) {
                    if (ld_coh_i32(abp) || it > PVALVE) {
                        st_coh_i32(abp, 1); lds_ab = 1; break;
                    }
                }
            }
            kbuf[par][cbase] = pval(a);
            kbuf[par][cbase + 64] = pval(b);
            kbuf[par][cbase + 128] = pval(c);
            kbuf[par][cbase + 192] = pval(d);
            __syncthreads();
            if (lds_ab) break;
            if (tid == 0) {
                if (t >= 1) {   // deferred output partial for step t-1 (off critical path)
                    const int q = (t - 1) & 1;
                    float s = osum[q][0] + osum[q][1] + osum[q][2] + osum[q][3] +
                              osum[q][4] + osum[q][5] + osum[q][6] + osum[q][7];
                    part[(size_t)(t - 1) * 128 + wgb] = s;
                }
                st_coh_i32(flags + wg * 4, t);   // consumed h0[t] + h1[t-1]
            }
            const int koff = (lane < 32) ? 0 : 1024;
            float hv[32];
#pragma unroll
            for (int j = 0; j < 32; ++j) hv[j] = kbuf[par][koff + hl + 32 * j];
            float acc[4];
#pragma unroll
            for (int g = 0; g < 4; ++g) {
                float s = 0.f;
#pragma unroll
                for (int k = 0; k < 32; ++k) s += w[g][k] * hv[k];
                acc[g] = s;
            }
#pragma unroll
            for (int g = 0; g < 4; ++g) acc[g] = wred(acc[g]);
            const float gi = acc[0] + bb[0];
            const float gf = acc[1] + bb[1];
            const float gg = acc[2] + bb[2];
            const float go = acc[3] + bb[3];
            const float cn = sigm(gf) * c1s + sigm(gi) * tanhf(gg);
            const float hn = sigm(go) * tanhf(cn);
            c1s = cn;
            if (t >= 48 && (t & 7) == 0) {
                long itf = 0;
                for (;;) {
                    int fl = ld_coh_i32(flp);
                    if (fl >= t - 40) break;
                    if (ld_coh_i32(abp)) break;
                    if (++itf > PVALVE) { st_coh_i32(abp, 1); break; }
                }
            }
            if (lane == 0) {
                st_pair(h1q + (size_t)(t & RMASK) * HDIM + e, pack(hn, t + 1));
                osum[t & 1][wv] = woute * hn;
            }
        }
        __syncthreads();
        if (tid == 0) {
            const int q = (T_STEPS - 1) & 1;
            float s = osum[q][0] + osum[q][1] + osum[q][2] + osum[q][3] +
                      osum[q][4] + osum[q][5] + osum[q][6] + osum[q][7];
            part[(size_t)(T_STEPS - 1) * 128 + wgb] = s;
            st_coh_i32(flags + wg * 4, T_STEPS);
        }
    }
}

// ---------- output projection: out[t] = b_out + sum_wb part[t][wb] ----------
__global__ void lstm_finalize(const float* __restrict__ part, const float* __restrict__ bout,
                              float* __restrict__ out) {
    const int t = blockIdx.x * 256 + threadIdx.x;
    if (t < T_STEPS) {
        const float4* p4 = (const float4*)(part + (size_t)t * 128);
        float s = bout[0];
#pragma unroll
        for (int i = 0; i < 32; ++i) {
            float4 v = p4[i];
            s += v.x + v.y + v.z + v.w;
        }
        out[t] = s;
    }
}

extern "C" void kernel_launch(void* const* d_in, const int* in_sizes, int n_in,
                              void* d_out, int out_size, void* d_ws, size_t ws_size,
                              hipStream_t stream) {
    const float* inputs = (const float*)d_in[0];
    const float* Win  = (const float*)d_in[1];
    const float* bin  = (const float*)d_in[2];
    const float* Wih0 = (const float*)d_in[3];
    const float* Whh0 = (const float*)d_in[4];
    const float* bih0 = (const float*)d_in[5];
    const float* bhh0 = (const float*)d_in[6];
    const float* Wih1 = (const float*)d_in[7];
    const float* Whh1 = (const float*)d_in[8];
    const float* bih1 = (const float*)d_in[9];
    const float* bhh1 = (const float*)d_in[10];
    const float* Wout = (const float*)d_in[11];
    const float* bout = (const float*)d_in[12];

    char* ws = (char*)d_ws;
    int*   flags = (int*)ws;                      // 4096 B: progress[wg*4], floor@768, abort@784
    u64*   h0q   = (u64*)(ws + 4096);             // 64*1024*8 = 512 KB
    u64*   h1q   = (u64*)(ws + 4096 + 524288);    // 512 KB (ends 1052672)
    float* U     = (float*)(ws + 1052672);        // 16 KB
    float* V     = (float*)(ws + 1069056);        // 16 KB
    float* B1    = (float*)(ws + 1085440);        // 16 KB (ends 1101824)
    float* part  = (float*)(ws + 1101824);        // 8192*128*4 = 4 MB (ends 5296128)

    if (ws_size < (size_t)5296128) return;

    hipMemsetAsync(ws, 0, 1052672, stream);       // flags + floor + abort + both rings

    lstm_prologue<<<1024, 256, 0, stream>>>(Wih0, Win, bin, bih0, bhh0, bih1, bhh1, U, V, B1);
    lstm_persistent<<<NWG + 1, 512, 0, stream>>>(inputs, Whh0, Wih1, Whh1, Wout,
                                                 flags, h0q, h1q, U, V, B1, part);
    lstm_finalize<<<(T_STEPS + 255) / 256, 256, 0, stream>>>(part, bout, (float*)d_out);
}